// Round 13
// baseline (234.819 us; speedup 1.0000x reference)
//
#include <hip/hip_runtime.h>
#include <hip/hip_bf16.h>

#define NSP   1568      // L*H*W
#define SEQ   1569      // 1 + NSP
#define CDIM  768
#define NHEAD 12
#define NTOT  6276      // B * SEQ
#define BATCH 4
#define NBH   48        // BATCH * NHEAD
#define SPADQ 1664      // padded q rows (26 * 64 = 13 * 128)
#define SPADK 1664      // padded keys  (13 * 128; tail zero-packed + masked)

typedef __bf16 bf16x8 __attribute__((ext_vector_type(8)));
typedef float  f32x4  __attribute__((ext_vector_type(4)));

static __device__ __forceinline__ unsigned pkbf(float a, float b) {
    __hip_bfloat16 ha = __float2bfloat16(a), hb = __float2bfloat16(b);
    return (unsigned)*(unsigned short*)&ha | ((unsigned)*(unsigned short*)&hb << 16);
}

// ---------------------------------------------------------------------------
// Fused prepass (one launch): z=0 Q, z=1 K, z=2 V, z=3 W.
// Q/K: [d][sp] fp32 (+cls at s=0) -> [bh][s][d] bf16 via LDS transpose;
//      Q pre-scaled by HD^-0.5 * log2(e).  V: -> [bh][d][s] bf16 (shifted).
// W:   [co][ci] fp32 -> bf16 cast.  K/V pads (s>=SEQ) written as zeros.
// ---------------------------------------------------------------------------
__global__ __launch_bounds__(256) void pack_all(
    const float* __restrict__ qg, const float* __restrict__ kg,
    const float* __restrict__ vg, const float* __restrict__ cq,
    const float* __restrict__ ck, const float* __restrict__ cv,
    const float* __restrict__ W,
    __hip_bfloat16* __restrict__ Qb, __hip_bfloat16* __restrict__ Kb,
    __hip_bfloat16* __restrict__ Vb, __hip_bfloat16* __restrict__ Wb)
{
    const int t  = threadIdx.x;
    const int z  = blockIdx.z;

    if (z == 3) {                       // W cast: 288 linear blocks of the 26x48 grid
        const int id = blockIdx.y * 26 + blockIdx.x;
        if (id >= 288) return;
        const size_t i = ((size_t)id * 256 + t) * 8;
        const float4 a = *(const float4*)(W + i);
        const float4 c = *(const float4*)(W + i + 4);
        __hip_bfloat16 hh[8] = {
            __float2bfloat16(a.x), __float2bfloat16(a.y),
            __float2bfloat16(a.z), __float2bfloat16(a.w),
            __float2bfloat16(c.x), __float2bfloat16(c.y),
            __float2bfloat16(c.z), __float2bfloat16(c.w)};
        *(uint4*)(Wb + i) = *(const uint4*)hh;
        return;
    }

    const int st = blockIdx.x;          // 64-row s-tile (0..25)
    const int bh = blockIdx.y;
    const int b = bh / NHEAD, h = bh % NHEAD;

    if (z == 2) {                       // V pack (no transpose), 26 tiles
        const float* g = vg + ((size_t)b * CDIM + h * 64) * NSP;
        const float* c = cv + b * CDIM + h * 64;
        const int sl = t & 63, s = st * 64 + sl;
        for (int i = 0; i < 16; ++i) {
            const int d = (t >> 6) * 16 + i;
            float v = 0.f;
            if (s == 0)       v = c[d];
            else if (s < SEQ) v = g[(size_t)d * NSP + s - 1];
            Vb[((size_t)bh * 64 + d) * SPADK + s] = __float2bfloat16(v);
        }
        return;
    }

    // z = 0/1: Q/K transpose-pack (26 tiles each; pads are zeros)
    __shared__ float tile[64 * 65];
    const float* g = (z ? kg : qg) + ((size_t)b * CDIM + h * 64) * NSP;
    const float* c = (z ? ck : cq) + b * CDIM + h * 64;
    const float scale = z ? 1.f : 0.125f * 1.44269504f;

    const int sl = t & 63, s = st * 64 + sl;
    for (int i = 0; i < 16; ++i) {
        const int d = (t >> 6) * 16 + i;
        float v = 0.f;
        if (s == 0)       v = c[d];
        else if (s < SEQ) v = g[(size_t)d * NSP + s - 1];
        tile[d * 65 + sl] = v * scale;
    }
    __syncthreads();
    __hip_bfloat16* out = z ? Kb : Qb;
    const size_t rowbase = (size_t)bh * (z ? SPADK : SPADQ) + st * 64;
    const int d = t & 63;
    for (int i = 0; i < 16; ++i) {
        const int r = i * 4 + (t >> 6);
        out[(rowbase + r) * 64 + d] = __float2bfloat16(tile[d * 65 + r]);
    }
}

// ---------------------------------------------------------------------------
// MFMA flash attention — r12 staging/barrier schedule (13 chunk-barriers,
// K dbuf 2x16KB, 128 q-rows/block) with 8 WAVES x 16 q each (512 threads).
// Total MFMA per staged chunk unchanged (8x18 = 4x36); staging traffic and
// barrier count unchanged; wave residency cap DOUBLES: 624 blocks x 8 waves
// = 19.5 waves/CU (vs 9.75). LDS 32K K + 8x2K P = 48KB -> 3 blocks/CU.
// Per-wave: Q frags in regs, V direct B-frags, wave-private P (no barrier),
// swapped-QK^T, no-rescale exp2 softmax, ones-column row sums.
// ---------------------------------------------------------------------------
__global__ __launch_bounds__(512, 3) void attn_mfma(
    const __hip_bfloat16* __restrict__ Qbp, const __hip_bfloat16* __restrict__ Kbp,
    const __hip_bfloat16* __restrict__ Vbp, __hip_bfloat16* __restrict__ xb)
{
    __shared__ char smem[49152];
    char* const Ksb0 = smem;            // [128 k][64 d] bf16 swizzled, chunk buf 0
    char* const Ksb1 = smem + 16384;    // chunk buf 1

    const int t    = threadIdx.x;
    const int lane = t & 63;
    const int w    = t >> 6;            // 0..7
    const int lo   = lane & 15, hi = lane >> 4;
    const int bh   = blockIdx.y;
    const int b    = bh / NHEAD, h = bh % NHEAD;
    const int qb   = blockIdx.x * 128;

    const unsigned short* Qg = (const unsigned short*)Qbp + ((size_t)bh * SPADQ + qb) * 64;
    const unsigned short* Kg = (const unsigned short*)Kbp + (size_t)bh * SPADK * 64;
    const unsigned short* Vg = (const unsigned short*)Vbp + (size_t)bh * 64 * SPADK;

    char* const Pw = smem + 32768 + w * 2048;   // per-wave [16 q][64 k] bf16 swz

    // ---- Q B-frags in registers, once: Q[q=qb+w*16+lo][d=(ks*4+hi)*8 ..]
    bf16x8 qf[2];
    #pragma unroll
    for (int ks = 0; ks < 2; ++ks)
        qf[ks] = *(const bf16x8*)(Qg + (w * 16 + lo) * 64 + (ks * 4 + hi) * 8);

    f32x4 o[4];             // O accumulators: row q=hi*4+r, col d=dn*16+lo
    f32x4 l5;               // row sums
    #pragma unroll
    for (int dn = 0; dn < 4; ++dn) o[dn] = (f32x4){0.f, 0.f, 0.f, 0.f};
    l5 = (f32x4){0.f, 0.f, 0.f, 0.f};

    bf16x8 ones;
    #pragma unroll
    for (int i = 0; i < 8; ++i) ones[i] = (__bf16)1.0f;

    // ---- K staging indices: 128 rows x 64 cols = 1024 x 16B chunks,
    //      512 threads x 2 chunks (rows sr, sr+64; col sc)
    const int sr = t >> 3, sc = t & 7;   // sr in [0,64)

    // ---- prologue: chunk 0 -> Ksb0
    uint4 kreg[2];
    #pragma unroll
    for (int p = 0; p < 2; ++p)
        kreg[p] = *(const uint4*)(Kg + (size_t)(sr + 64 * p) * 64 + sc * 8);
    #pragma unroll
    for (int p = 0; p < 2; ++p) {
        const int r = sr + 64 * p;
        *(uint4*)(Ksb0 + r * 128 + ((sc ^ (r & 7)) * 16)) = kreg[p];
    }

    int cur = 0;

    for (int it = 0; it < 13; ++it) {
        __syncthreads();                        // chunk[cur] staged for all waves
        char* const Kcur = cur ? Ksb1 : Ksb0;
        char* const Knxt = cur ? Ksb0 : Ksb1;

        // prefetch next 128-key chunk into regs (clamped; last iter redundant)
        const int itn = (it + 1 < 13) ? it + 1 : it;
        #pragma unroll
        for (int p = 0; p < 2; ++p)
            kreg[p] = *(const uint4*)(Kg + (size_t)(itn * 128 + sr + 64 * p) * 64 + sc * 8);

        // ---- two 64-key subtiles from the staged chunk
        #pragma unroll
        for (int sub = 0; sub < 2; ++sub) {
            const int kb = it * 128 + sub * 64;
            char* const Ksub = Kcur + sub * 8192;

            // V B-frags ks=0 (direct global; independent, overlaps QK)
            uint4 vf0[4];
            #pragma unroll
            for (int dn = 0; dn < 4; ++dn)
                vf0[dn] = *(const uint4*)(Vg + (size_t)(dn * 16 + lo) * SPADK + kb + hi * 8);

            // ---- S^T = K Q^T (A=K rows k from LDS, B=Q cols q from regs)
            f32x4 s[4];
            #pragma unroll
            for (int km = 0; km < 4; ++km) s[km] = (f32x4){0.f, 0.f, 0.f, 0.f};
            #pragma unroll
            for (int ks = 0; ks < 2; ++ks) {
                bf16x8 ak[4];
                #pragma unroll
                for (int km = 0; km < 4; ++km)
                    ak[km] = *(const bf16x8*)(Ksub + (km * 16 + lo) * 128 + (((ks * 4 + hi) ^ (lo & 7)) * 16));
                #pragma unroll
                for (int km = 0; km < 4; ++km)
                    s[km] = __builtin_amdgcn_mfma_f32_16x16x32_bf16(ak[km], qf[ks], s[km], 0, 0, 0);
            }

            if (it == 12) {                     // chunk 12: keys 1536..1663, mask k >= SEQ
                #pragma unroll
                for (int km = 0; km < 4; ++km)
                    #pragma unroll
                    for (int r = 0; r < 4; ++r)
                        if (kb + km * 16 + hi * 4 + r >= SEQ) s[km][r] = -1e30f;
            }

            // ---- P = exp2(S) -> per-wave LDS, packed b64, swizzled
            // lane holds k = km*16 + hi*4 + 0..3 at fixed q = lo
            #pragma unroll
            for (int km = 0; km < 4; ++km) {
                const float p0 = exp2f(s[km][0]);
                const float p1 = exp2f(s[km][1]);
                const float p2 = exp2f(s[km][2]);
                const float p3 = exp2f(s[km][3]);
                uint2 pk;
                pk.x = pkbf(p0, p1);
                pk.y = pkbf(p2, p3);
                *(uint2*)(Pw + lo * 128 + (((km * 2 + (hi >> 1)) ^ (lo & 7)) * 16) + (hi & 1) * 8) = pk;
            }

            // V B-frags ks=1
            uint4 vf1[4];
            #pragma unroll
            for (int dn = 0; dn < 4; ++dn)
                vf1[dn] = *(const uint4*)(Vg + (size_t)(dn * 16 + lo) * SPADK + kb + 32 + hi * 8);

            // ---- O += P V ; l += P * ones  (P wave-private: no barrier)
            #pragma unroll
            for (int ks = 0; ks < 2; ++ks) {
                const bf16x8 ap = *(const bf16x8*)(Pw + lo * 128 + (((ks * 4 + hi) ^ (lo & 7)) * 16));
                #pragma unroll
                for (int dn = 0; dn < 4; ++dn) {
                    const bf16x8 bv = *(const bf16x8*)(ks ? &vf1[dn] : &vf0[dn]);
                    o[dn] = __builtin_amdgcn_mfma_f32_16x16x32_bf16(ap, bv, o[dn], 0, 0, 0);
                }
                l5 = __builtin_amdgcn_mfma_f32_16x16x32_bf16(ap, ones, l5, 0, 0, 0);
            }
        }

        // stage next chunk into the other buffer (visible after next barrier)
        #pragma unroll
        for (int p = 0; p < 2; ++p) {
            const int r = sr + 64 * p;
            *(uint4*)(Knxt + r * 128 + ((sc ^ (r & 7)) * 16)) = kreg[p];
        }
        cur ^= 1;
    }

    // ---- epilogue: normalize by row sum, direct bf16 stores to xb[n][ci]
    #pragma unroll
    for (int r = 0; r < 4; ++r) {
        const float inv = 1.f / l5[r];
        const int q = qb + w * 16 + hi * 4 + r;
        if (q < SEQ) {
            __hip_bfloat16* dst = xb + ((size_t)b * SEQ + q) * CDIM + h * 64 + lo;
            #pragma unroll
            for (int dn = 0; dn < 4; ++dn)
                dst[dn * 16] = __float2bfloat16(o[dn][r] * inv);
        }
    }
}

// ---------------------------------------------------------------------------
// MFMA projection, 128co x 64n tiles. 4 waves: (w>>1) = co half, (w&1) =
// n half (32). K-step 64, reg prefetch, XOR-swizzled LDS. Guarded x-loads.
// ---------------------------------------------------------------------------
__global__ __launch_bounds__(256) void proj_mfma(
    const __hip_bfloat16* __restrict__ Wb, const __hip_bfloat16* __restrict__ xbp,
    const float* __restrict__ bias, float* __restrict__ xout,
    float* __restrict__ clsout)
{
    __shared__ char smem[24576];
    char* Ws = smem;            // [128 co][64 k] bf16, swizzled
    char* Xs = smem + 16384;    // [ 64 n][64 k] bf16, swizzled

    const int t    = threadIdx.x;
    const int lane = t & 63;
    const int w    = t >> 6;
    const int lo   = lane & 15, hi = lane >> 4;
    const int nb   = blockIdx.x * 64;
    const int mb   = blockIdx.y * 128;

    const unsigned short* Wg = (const unsigned short*)Wb  + (size_t)mb * CDIM;
    const unsigned short* Xg = (const unsigned short*)xbp + (size_t)nb * CDIM;

    f32x4 acc[4][2];
    #pragma unroll
    for (int m = 0; m < 4; ++m)
        #pragma unroll
        for (int n = 0; n < 2; ++n) acc[m][n] = (f32x4){0.f, 0.f, 0.f, 0.f};

    const bool xok[2] = { nb + ((t)       >> 3) < NTOT,
                          nb + ((t + 256) >> 3) < NTOT };
    uint4 wreg[4], xreg[2];
    #pragma unroll
    for (int p = 0; p < 4; ++p) {
        const int ch = t + 256 * p;
        wreg[p] = *(const uint4*)(Wg + (ch >> 3) * CDIM + (ch & 7) * 8);
    }
    #pragma unroll
    for (int p = 0; p < 2; ++p) {
        const int ch = t + 256 * p;
        xreg[p] = xok[p] ? *(const uint4*)(Xg + (ch >> 3) * CDIM + (ch & 7) * 8)
                         : (uint4){0u, 0u, 0u, 0u};
    }

    for (int kt = 0; kt < 12; ++kt) {
        __syncthreads();
        #pragma unroll
        for (int p = 0; p < 4; ++p) {
            const int ch = t + 256 * p;
            const int r = ch >> 3, c = ch & 7;
            *(uint4*)(Ws + r * 128 + ((c ^ (r & 7)) * 16)) = wreg[p];
        }
        #pragma unroll
        for (int p = 0; p < 2; ++p) {
            const int ch = t + 256 * p;
            const int r = ch >> 3, c = ch & 7;
            *(uint4*)(Xs + r * 128 + ((c ^ (r & 7)) * 16)) = xreg[p];
        }
        __syncthreads();
        if (kt + 1 < 12) {
            const int kb = (kt + 1) * 64;
            #pragma unroll
            for (int p = 0; p < 4; ++p) {
                const int ch = t + 256 * p;
                wreg[p] = *(const uint4*)(Wg + (ch >> 3) * CDIM + kb + (ch & 7) * 8);
            }
            #pragma unroll
            for (int p = 0; p < 2; ++p) {
                const int ch = t + 256 * p;
                xreg[p] = xok[p] ? *(const uint4*)(Xg + (ch >> 3) * CDIM + kb + (ch & 7) * 8)
                                 : (uint4){0u, 0u, 0u, 0u};
            }
        }
        #pragma unroll
        for (int ks = 0; ks < 2; ++ks) {
            bf16x8 aw[4], bx[2];
            #pragma unroll
            for (int m = 0; m < 4; ++m) {
                const int row = (w >> 1) * 64 + m * 16 + lo;
                aw[m] = *(const bf16x8*)(Ws + row * 128 + (((ks * 4 + hi) ^ (lo & 7)) * 16));
            }
            #pragma unroll
            for (int n = 0; n < 2; ++n) {
                const int row = (w & 1) * 32 + n * 16 + lo;
                bx[n] = *(const bf16x8*)(Xs + row * 128 + (((ks * 4 + hi) ^ (lo & 7)) * 16));
            }
            #pragma unroll
            for (int m = 0; m < 4; ++m)
                #pragma unroll
                for (int n = 0; n < 2; ++n)
                    acc[m][n] = __builtin_amdgcn_mfma_f32_16x16x32_bf16(aw[m], bx[n], acc[m][n], 0, 0, 0);
        }
    }

    // ---- epilogue: bias, scatter (s==0 -> cls, else spatial, co-major)
    const int cob = mb + (w >> 1) * 64;
    const int nbb = nb + (w & 1) * 32;
    #pragma unroll
    for (int m = 0; m < 4; ++m)
        #pragma unroll
        for (int r = 0; r < 4; ++r) {
            const int co = cob + m * 16 + hi * 4 + r;
            const float bv = bias[co];
            #pragma unroll
            for (int n4 = 0; n4 < 2; ++n4) {
                const int n = nbb + n4 * 16 + lo;
                if (n >= NTOT) continue;
                const int bq = n / SEQ;
                const int s  = n - bq * SEQ;
                const float val = acc[m][n4][r] + bv;
                if (s == 0) clsout[bq * CDIM + co] = val;
                else        xout[((size_t)bq * CDIM + co) * NSP + (s - 1)] = val;
            }
        }
}

extern "C" void kernel_launch(void* const* d_in, const int* in_sizes, int n_in,
                              void* d_out, int out_size, void* d_ws, size_t ws_size,
                              hipStream_t stream)
{
    const float* q  = (const float*)d_in[0];
    const float* k  = (const float*)d_in[1];
    const float* v  = (const float*)d_in[2];
    const float* cq = (const float*)d_in[3];
    const float* ck = (const float*)d_in[4];
    const float* cv = (const float*)d_in[5];
    const float* W  = (const float*)d_in[6];
    const float* bi = (const float*)d_in[7];

    float* out    = (float*)d_out;
    float* xout   = out;
    float* clsout = out + (size_t)BATCH * CDIM * NSP;

    __hip_bfloat16* Qb = (__hip_bfloat16*)d_ws;                 // 10.2 MB
    __hip_bfloat16* Kb = Qb + (size_t)NBH * SPADQ * 64;         // 10.2 MB
    __hip_bfloat16* Vb = Kb + (size_t)NBH * SPADK * 64;         // 10.2 MB
    __hip_bfloat16* Wb = Vb + (size_t)NBH * 64 * SPADK;         //  1.2 MB
    __hip_bfloat16* xb = Wb + (size_t)CDIM * CDIM;              //  9.6 MB

    pack_all <<<dim3(26, NBH, 4), 256, 0, stream>>>(q, k, v, cq, ck, cv, W,
                                                    Qb, Kb, Vb, Wb);
    attn_mfma<<<dim3(13, NBH),    512, 0, stream>>>(Qb, Kb, Vb, xb);
    proj_mfma<<<dim3(99, 6),      256, 0, stream>>>(Wb, xb, bi, xout, clsout);
}

// Round 14
// 152.788 us; speedup vs baseline: 1.5369x; 1.5369x over previous
//
#include <hip/hip_runtime.h>
#include <hip/hip_bf16.h>

#define NSP   1568      // L*H*W
#define SEQ   1569      // 1 + NSP
#define CDIM  768
#define NHEAD 12
#define NTOT  6276      // B * SEQ
#define BATCH 4
#define NBH   48        // BATCH * NHEAD
#define SPADQ 1664      // padded q rows (26 * 64 = 13 * 128)
#define SPADK 1664      // padded keys  (13 * 128; tail zero-packed + masked)

typedef __bf16 bf16x8 __attribute__((ext_vector_type(8)));
typedef float  f32x4  __attribute__((ext_vector_type(4)));

static __device__ __forceinline__ unsigned pkbf(float a, float b) {
    __hip_bfloat16 ha = __float2bfloat16(a), hb = __float2bfloat16(b);
    return (unsigned)*(unsigned short*)&ha | ((unsigned)*(unsigned short*)&hb << 16);
}

// ---------------------------------------------------------------------------
// Fused prepass (one launch): z=0 Q, z=1 K, z=2 V, z=3 W.
// Q/K: [d][sp] fp32 (+cls at s=0) -> [bh][s][d] bf16 via LDS transpose;
//      Q pre-scaled by HD^-0.5 * log2(e).  V: -> [bh][d][s] bf16 (shifted).
// W:   [co][ci] fp32 -> bf16 cast.  K/V pads (s>=SEQ) written as zeros.
// ---------------------------------------------------------------------------
__global__ __launch_bounds__(256) void pack_all(
    const float* __restrict__ qg, const float* __restrict__ kg,
    const float* __restrict__ vg, const float* __restrict__ cq,
    const float* __restrict__ ck, const float* __restrict__ cv,
    const float* __restrict__ W,
    __hip_bfloat16* __restrict__ Qb, __hip_bfloat16* __restrict__ Kb,
    __hip_bfloat16* __restrict__ Vb, __hip_bfloat16* __restrict__ Wb)
{
    const int t  = threadIdx.x;
    const int z  = blockIdx.z;

    if (z == 3) {                       // W cast: 288 linear blocks of the 26x48 grid
        const int id = blockIdx.y * 26 + blockIdx.x;
        if (id >= 288) return;
        const size_t i = ((size_t)id * 256 + t) * 8;
        const float4 a = *(const float4*)(W + i);
        const float4 c = *(const float4*)(W + i + 4);
        __hip_bfloat16 hh[8] = {
            __float2bfloat16(a.x), __float2bfloat16(a.y),
            __float2bfloat16(a.z), __float2bfloat16(a.w),
            __float2bfloat16(c.x), __float2bfloat16(c.y),
            __float2bfloat16(c.z), __float2bfloat16(c.w)};
        *(uint4*)(Wb + i) = *(const uint4*)hh;
        return;
    }

    const int st = blockIdx.x;          // 64-row s-tile (0..25)
    const int bh = blockIdx.y;
    const int b = bh / NHEAD, h = bh % NHEAD;

    if (z == 2) {                       // V pack (no transpose), 26 tiles
        const float* g = vg + ((size_t)b * CDIM + h * 64) * NSP;
        const float* c = cv + b * CDIM + h * 64;
        const int sl = t & 63, s = st * 64 + sl;
        for (int i = 0; i < 16; ++i) {
            const int d = (t >> 6) * 16 + i;
            float v = 0.f;
            if (s == 0)       v = c[d];
            else if (s < SEQ) v = g[(size_t)d * NSP + s - 1];
            Vb[((size_t)bh * 64 + d) * SPADK + s] = __float2bfloat16(v);
        }
        return;
    }

    // z = 0/1: Q/K transpose-pack (26 tiles each; pads are zeros)
    __shared__ float tile[64 * 65];
    const float* g = (z ? kg : qg) + ((size_t)b * CDIM + h * 64) * NSP;
    const float* c = (z ? ck : cq) + b * CDIM + h * 64;
    const float scale = z ? 1.f : 0.125f * 1.44269504f;

    const int sl = t & 63, s = st * 64 + sl;
    for (int i = 0; i < 16; ++i) {
        const int d = (t >> 6) * 16 + i;
        float v = 0.f;
        if (s == 0)       v = c[d];
        else if (s < SEQ) v = g[(size_t)d * NSP + s - 1];
        tile[d * 65 + sl] = v * scale;
    }
    __syncthreads();
    __hip_bfloat16* out = z ? Kb : Qb;
    const size_t rowbase = (size_t)bh * (z ? SPADK : SPADQ) + st * 64;
    const int d = t & 63;
    for (int i = 0; i < 16; ++i) {
        const int r = i * 4 + (t >> 6);
        out[(rowbase + r) * 64 + d] = __float2bfloat16(tile[d * 65 + r]);
    }
}

// ---------------------------------------------------------------------------
// MFMA flash attention — r12 VERBATIM (validated best: 102.6 us) plus two
// orthogonal micro-levers, no structural change:
//  (1) XCD-aware bh-grouped 1D grid: 624 = 8 XCD x (6 bh x 13 qt). All 13
//      q-blocks of one bh land on ONE XCD -> its K/V (426 KB; 6 bh = 2.6 MB
//      < 4 MB L2) is fetched from HBM once per XCD instead of ~8x.
//  (2) s_setprio(1) around QK and PV MFMA clusters (T5): waves free-run
//      between barriers at different phases, so prio steers the CU scheduler
//      to keep the matrix pipe fed while other waves do exp2/staging.
// Schedule: 13 chunk-barriers, K dbuf 2x16KB, 4 waves x 32 q, V direct,
// wave-private P, swapped-QK^T, no-rescale exp2 softmax, ones-column sums.
// ---------------------------------------------------------------------------
__global__ __launch_bounds__(256, 3) void attn_mfma(
    const __hip_bfloat16* __restrict__ Qbp, const __hip_bfloat16* __restrict__ Kbp,
    const __hip_bfloat16* __restrict__ Vbp, __hip_bfloat16* __restrict__ xb)
{
    __shared__ char smem[49152];
    char* const Ksb0 = smem;            // [128 k][64 d] bf16 swizzled, chunk buf 0
    char* const Ksb1 = smem + 16384;    // chunk buf 1

    const int t    = threadIdx.x;
    const int lane = t & 63;
    const int w    = t >> 6;
    const int lo   = lane & 15, hi = lane >> 4;

    // ---- XCD-grouped decode: gid&7 = XCD (round-robin dispatch), each XCD
    //      owns 6 whole bh (slot/13) x 13 q-tiles (slot%13). Bijective: 624=8*78.
    const int gid  = blockIdx.x;
    const int slot = gid >> 3;
    const int bh   = (gid & 7) + 8 * (slot / 13);
    const int qb   = (slot % 13) * 128;
    const int b    = bh / NHEAD, h = bh % NHEAD;

    const unsigned short* Qg = (const unsigned short*)Qbp + ((size_t)bh * SPADQ + qb) * 64;
    const unsigned short* Kg = (const unsigned short*)Kbp + (size_t)bh * SPADK * 64;
    const unsigned short* Vg = (const unsigned short*)Vbp + (size_t)bh * 64 * SPADK;

    char* const Pw = smem + 32768 + w * 4096;   // per-wave [32 q][64 k] bf16 swz

    // ---- Q fragments in registers, once
    bf16x8 qf[2][2];
    #pragma unroll
    for (int qn = 0; qn < 2; ++qn)
        #pragma unroll
        for (int ks = 0; ks < 2; ++ks)
            qf[qn][ks] = *(const bf16x8*)(Qg + (w * 32 + qn * 16 + lo) * 64 + (ks * 4 + hi) * 8);

    f32x4 o[2][4];          // O accumulators: row q=hi*4+r, col d=dn*16+lo
    f32x4 l5[2];            // row-sum accumulators
    #pragma unroll
    for (int m = 0; m < 2; ++m) {
        l5[m] = (f32x4){0.f, 0.f, 0.f, 0.f};
        #pragma unroll
        for (int n = 0; n < 4; ++n) o[m][n] = (f32x4){0.f, 0.f, 0.f, 0.f};
    }

    bf16x8 ones;
    #pragma unroll
    for (int i = 0; i < 8; ++i) ones[i] = (__bf16)1.0f;

    // ---- K staging indices: 128 rows x 64 cols = 1024 x 16B chunks,
    //      256 threads x 4 chunks (rows sr + 32p, col sc)
    const int sr = t >> 3, sc = t & 7;   // sr in [0,32)

    // ---- prologue: chunk 0 -> Ksb0
    uint4 kreg[4];
    #pragma unroll
    for (int p = 0; p < 4; ++p)
        kreg[p] = *(const uint4*)(Kg + (size_t)(sr + 32 * p) * 64 + sc * 8);
    #pragma unroll
    for (int p = 0; p < 4; ++p) {
        const int r = sr + 32 * p;
        *(uint4*)(Ksb0 + r * 128 + ((sc ^ (r & 7)) * 16)) = kreg[p];
    }

    int cur = 0;

    for (int it = 0; it < 13; ++it) {
        __syncthreads();                        // chunk[cur] staged for all waves
        char* const Kcur = cur ? Ksb1 : Ksb0;
        char* const Knxt = cur ? Ksb0 : Ksb1;

        // prefetch next 128-key chunk into regs (clamped; last iter redundant)
        const int itn = (it + 1 < 13) ? it + 1 : it;
        #pragma unroll
        for (int p = 0; p < 4; ++p)
            kreg[p] = *(const uint4*)(Kg + (size_t)(itn * 128 + sr + 32 * p) * 64 + sc * 8);

        // ---- two 64-key subtiles from the staged chunk
        #pragma unroll
        for (int sub = 0; sub < 2; ++sub) {
            const int kb = it * 128 + sub * 64;
            char* const Ksub = Kcur + sub * 8192;

            // V fragments ks=0 (direct global, B-frag)
            uint4 vf0[4];
            #pragma unroll
            for (int dn = 0; dn < 4; ++dn)
                vf0[dn] = *(const uint4*)(Vg + (size_t)(dn * 16 + lo) * SPADK + kb + hi * 8);

            // ---- S^T = K Q^T  (prio-boosted MFMA cluster)
            f32x4 s[4][2];
            #pragma unroll
            for (int km = 0; km < 4; ++km)
                #pragma unroll
                for (int qn = 0; qn < 2; ++qn) s[km][qn] = (f32x4){0.f, 0.f, 0.f, 0.f};
            __builtin_amdgcn_s_setprio(1);
            #pragma unroll
            for (int ks = 0; ks < 2; ++ks) {
                bf16x8 ak[4];
                #pragma unroll
                for (int km = 0; km < 4; ++km)
                    ak[km] = *(const bf16x8*)(Ksub + (km * 16 + lo) * 128 + (((ks * 4 + hi) ^ (lo & 7)) * 16));
                #pragma unroll
                for (int km = 0; km < 4; ++km)
                    #pragma unroll
                    for (int qn = 0; qn < 2; ++qn)
                        s[km][qn] = __builtin_amdgcn_mfma_f32_16x16x32_bf16(ak[km], qf[qn][ks], s[km][qn], 0, 0, 0);
            }
            __builtin_amdgcn_s_setprio(0);

            if (it == 12) {                     // chunk 12: keys 1536..1663, mask k >= SEQ
                #pragma unroll
                for (int km = 0; km < 4; ++km)
                    #pragma unroll
                    for (int r = 0; r < 4; ++r)
                        if (kb + km * 16 + hi * 4 + r >= SEQ) {
                            s[km][0][r] = -1e30f;
                            s[km][1][r] = -1e30f;
                        }
            }

            // ---- P = exp2(S); packed b64 writes into Pw[q][k] (swizzled)
            #pragma unroll
            for (int qn = 0; qn < 2; ++qn)
                #pragma unroll
                for (int km = 0; km < 4; ++km) {
                    const float p0 = exp2f(s[km][qn][0]);
                    const float p1 = exp2f(s[km][qn][1]);
                    const float p2 = exp2f(s[km][qn][2]);
                    const float p3 = exp2f(s[km][qn][3]);
                    uint2 pk;
                    pk.x = pkbf(p0, p1);
                    pk.y = pkbf(p2, p3);
                    const int row = qn * 16 + lo;
                    *(uint2*)(Pw + row * 128 + (((km * 2 + (hi >> 1)) ^ (lo & 7)) * 16) + (hi & 1) * 8) = pk;
                }

            // V fragments ks=1
            uint4 vf1[4];
            #pragma unroll
            for (int dn = 0; dn < 4; ++dn)
                vf1[dn] = *(const uint4*)(Vg + (size_t)(dn * 16 + lo) * SPADK + kb + 32 + hi * 8);

            // ---- O += P V ; l += P * ones  (prio-boosted MFMA cluster)
            __builtin_amdgcn_s_setprio(1);
            #pragma unroll
            for (int ks = 0; ks < 2; ++ks) {
                bf16x8 ap[2];
                #pragma unroll
                for (int m = 0; m < 2; ++m)
                    ap[m] = *(const bf16x8*)(Pw + (m * 16 + lo) * 128 + (((ks * 4 + hi) ^ (lo & 7)) * 16));
                #pragma unroll
                for (int m = 0; m < 2; ++m) {
                    #pragma unroll
                    for (int dn = 0; dn < 4; ++dn) {
                        const bf16x8 bv = *(const bf16x8*)(ks ? &vf1[dn] : &vf0[dn]);
                        o[m][dn] = __builtin_amdgcn_mfma_f32_16x16x32_bf16(ap[m], bv, o[m][dn], 0, 0, 0);
                    }
                    l5[m] = __builtin_amdgcn_mfma_f32_16x16x32_bf16(ap[m], ones, l5[m], 0, 0, 0);
                }
            }
            __builtin_amdgcn_s_setprio(0);
        }

        // stage next chunk into the other buffer (visible after next barrier)
        #pragma unroll
        for (int p = 0; p < 4; ++p) {
            const int r = sr + 32 * p;
            *(uint4*)(Knxt + r * 128 + ((sc ^ (r & 7)) * 16)) = kreg[p];
        }
        cur ^= 1;
    }

    // ---- epilogue: normalize by row sum, direct bf16 stores to xb[n][ci]
    #pragma unroll
    for (int m = 0; m < 2; ++m)
        #pragma unroll
        for (int r = 0; r < 4; ++r) {
            const float inv = 1.f / l5[m][r];
            const int q = qb + w * 32 + m * 16 + hi * 4 + r;
            if (q < SEQ) {
                __hip_bfloat16* dst = xb + ((size_t)b * SEQ + q) * CDIM + h * 64 + lo;
                #pragma unroll
                for (int dn = 0; dn < 4; ++dn)
                    dst[dn * 16] = __float2bfloat16(o[m][dn][r] * inv);
            }
        }
}

// ---------------------------------------------------------------------------
// MFMA projection, 128co x 64n tiles. 4 waves: (w>>1) = co half, (w&1) =
// n half (32). K-step 64, reg prefetch, XOR-swizzled LDS. Guarded x-loads.
// ---------------------------------------------------------------------------
__global__ __launch_bounds__(256) void proj_mfma(
    const __hip_bfloat16* __restrict__ Wb, const __hip_bfloat16* __restrict__ xbp,
    const float* __restrict__ bias, float* __restrict__ xout,
    float* __restrict__ clsout)
{
    __shared__ char smem[24576];
    char* Ws = smem;            // [128 co][64 k] bf16, swizzled
    char* Xs = smem + 16384;    // [ 64 n][64 k] bf16, swizzled

    const int t    = threadIdx.x;
    const int lane = t & 63;
    const int w    = t >> 6;
    const int lo   = lane & 15, hi = lane >> 4;
    const int nb   = blockIdx.x * 64;
    const int mb   = blockIdx.y * 128;

    const unsigned short* Wg = (const unsigned short*)Wb  + (size_t)mb * CDIM;
    const unsigned short* Xg = (const unsigned short*)xbp + (size_t)nb * CDIM;

    f32x4 acc[4][2];
    #pragma unroll
    for (int m = 0; m < 4; ++m)
        #pragma unroll
        for (int n = 0; n < 2; ++n) acc[m][n] = (f32x4){0.f, 0.f, 0.f, 0.f};

    const bool xok[2] = { nb + ((t)       >> 3) < NTOT,
                          nb + ((t + 256) >> 3) < NTOT };
    uint4 wreg[4], xreg[2];
    #pragma unroll
    for (int p = 0; p < 4; ++p) {
        const int ch = t + 256 * p;
        wreg[p] = *(const uint4*)(Wg + (ch >> 3) * CDIM + (ch & 7) * 8);
    }
    #pragma unroll
    for (int p = 0; p < 2; ++p) {
        const int ch = t + 256 * p;
        xreg[p] = xok[p] ? *(const uint4*)(Xg + (ch >> 3) * CDIM + (ch & 7) * 8)
                         : (uint4){0u, 0u, 0u, 0u};
    }

    for (int kt = 0; kt < 12; ++kt) {
        __syncthreads();
        #pragma unroll
        for (int p = 0; p < 4; ++p) {
            const int ch = t + 256 * p;
            const int r = ch >> 3, c = ch & 7;
            *(uint4*)(Ws + r * 128 + ((c ^ (r & 7)) * 16)) = wreg[p];
        }
        #pragma unroll
        for (int p = 0; p < 2; ++p) {
            const int ch = t + 256 * p;
            const int r = ch >> 3, c = ch & 7;
            *(uint4*)(Xs + r * 128 + ((c ^ (r & 7)) * 16)) = xreg[p];
        }
        __syncthreads();
        if (kt + 1 < 12) {
            const int kb = (kt + 1) * 64;
            #pragma unroll
            for (int p = 0; p < 4; ++p) {
                const int ch = t + 256 * p;
                wreg[p] = *(const uint4*)(Wg + (ch >> 3) * CDIM + kb + (ch & 7) * 8);
            }
            #pragma unroll
            for (int p = 0; p < 2; ++p) {
                const int ch = t + 256 * p;
                xreg[p] = xok[p] ? *(const uint4*)(Xg + (ch >> 3) * CDIM + kb + (ch & 7) * 8)
                                 : (uint4){0u, 0u, 0u, 0u};
            }
        }
        #pragma unroll
        for (int ks = 0; ks < 2; ++ks) {
            bf16x8 aw[4], bx[2];
            #pragma unroll
            for (int m = 0; m < 4; ++m) {
                const int row = (w >> 1) * 64 + m * 16 + lo;
                aw[m] = *(const bf16x8*)(Ws + row * 128 + (((ks * 4 + hi) ^ (lo & 7)) * 16));
            }
            #pragma unroll
            for (int n = 0; n < 2; ++n) {
                const int row = (w & 1) * 32 + n * 16 + lo;
                bx[n] = *(const bf16x8*)(Xs + row * 128 + (((ks * 4 + hi) ^ (lo & 7)) * 16));
            }
            #pragma unroll
            for (int m = 0; m < 4; ++m)
                #pragma unroll
                for (int n = 0; n < 2; ++n)
                    acc[m][n] = __builtin_amdgcn_mfma_f32_16x16x32_bf16(aw[m], bx[n], acc[m][n], 0, 0, 0);
        }
    }

    // ---- epilogue: bias, scatter (s==0 -> cls, else spatial, co-major)
    const int cob = mb + (w >> 1) * 64;
    const int nbb = nb + (w & 1) * 32;
    #pragma unroll
    for (int m = 0; m < 4; ++m)
        #pragma unroll
        for (int r = 0; r < 4; ++r) {
            const int co = cob + m * 16 + hi * 4 + r;
            const float bv = bias[co];
            #pragma unroll
            for (int n4 = 0; n4 < 2; ++n4) {
                const int n = nbb + n4 * 16 + lo;
                if (n >= NTOT) continue;
                const int bq = n / SEQ;
                const int s  = n - bq * SEQ;
                const float val = acc[m][n4][r] + bv;
                if (s == 0) clsout[bq * CDIM + co] = val;
                else        xout[((size_t)bq * CDIM + co) * NSP + (s - 1)] = val;
            }
        }
}

extern "C" void kernel_launch(void* const* d_in, const int* in_sizes, int n_in,
                              void* d_out, int out_size, void* d_ws, size_t ws_size,
                              hipStream_t stream)
{
    const float* q  = (const float*)d_in[0];
    const float* k  = (const float*)d_in[1];
    const float* v  = (const float*)d_in[2];
    const float* cq = (const float*)d_in[3];
    const float* ck = (const float*)d_in[4];
    const float* cv = (const float*)d_in[5];
    const float* W  = (const float*)d_in[6];
    const float* bi = (const float*)d_in[7];

    float* out    = (float*)d_out;
    float* xout   = out;
    float* clsout = out + (size_t)BATCH * CDIM * NSP;

    __hip_bfloat16* Qb = (__hip_bfloat16*)d_ws;                 // 10.2 MB
    __hip_bfloat16* Kb = Qb + (size_t)NBH * SPADQ * 64;         // 10.2 MB
    __hip_bfloat16* Vb = Kb + (size_t)NBH * SPADK * 64;         // 10.2 MB
    __hip_bfloat16* Wb = Vb + (size_t)NBH * 64 * SPADK;         //  1.2 MB
    __hip_bfloat16* xb = Wb + (size_t)CDIM * CDIM;              //  9.6 MB

    pack_all <<<dim3(26, NBH, 4), 256, 0, stream>>>(q, k, v, cq, ck, cv, W,
                                                    Qb, Kb, Vb, Wb);
    attn_mfma<<<dim3(624),        256, 0, stream>>>(Qb, Kb, Vb, xb);
    proj_mfma<<<dim3(99, 6),      256, 0, stream>>>(Wb, xb, bi, xout, clsout);
}

// Round 15
// 152.593 us; speedup vs baseline: 1.5389x; 1.0013x over previous
//
#include <hip/hip_runtime.h>
#include <hip/hip_bf16.h>

#define NSP   1568      // L*H*W
#define SEQ   1569      // 1 + NSP
#define CDIM  768
#define NHEAD 12
#define NTOT  6276      // B * SEQ
#define BATCH 4
#define NBH   48        // BATCH * NHEAD
#define SPADQ 1664      // padded q rows (26 * 64 = 13 * 128)
#define SPADK 1664      // padded keys  (13 * 128; tail zero-packed + masked)

typedef __bf16 bf16x8 __attribute__((ext_vector_type(8)));
typedef float  f32x4  __attribute__((ext_vector_type(4)));

static __device__ __forceinline__ unsigned pkbf(float a, float b) {
    __hip_bfloat16 ha = __float2bfloat16(a), hb = __float2bfloat16(b);
    return (unsigned)*(unsigned short*)&ha | ((unsigned)*(unsigned short*)&hb << 16);
}

// ---------------------------------------------------------------------------
// Fused prepass: z=0 K, z=1 V, z=2 W.  (Q-pack folded into attn_mfma.)
// K: [d][sp] fp32 (+cls at s=0) -> [bh][s][d] bf16 via LDS transpose.
// V: -> [bh][d][s] bf16 (shifted).  W: [co][ci] fp32 -> bf16 cast.
// K/V pads (s>=SEQ) written as zeros.
// ---------------------------------------------------------------------------
__global__ __launch_bounds__(256) void pack_all(
    const float* __restrict__ kg, const float* __restrict__ vg,
    const float* __restrict__ ck, const float* __restrict__ cv,
    const float* __restrict__ W,
    __hip_bfloat16* __restrict__ Kb, __hip_bfloat16* __restrict__ Vb,
    __hip_bfloat16* __restrict__ Wb)
{
    const int t  = threadIdx.x;
    const int z  = blockIdx.z;

    if (z == 2) {                       // W cast: 288 linear blocks of the 26x48 grid
        const int id = blockIdx.y * 26 + blockIdx.x;
        if (id >= 288) return;
        const size_t i = ((size_t)id * 256 + t) * 8;
        const float4 a = *(const float4*)(W + i);
        const float4 c = *(const float4*)(W + i + 4);
        __hip_bfloat16 hh[8] = {
            __float2bfloat16(a.x), __float2bfloat16(a.y),
            __float2bfloat16(a.z), __float2bfloat16(a.w),
            __float2bfloat16(c.x), __float2bfloat16(c.y),
            __float2bfloat16(c.z), __float2bfloat16(c.w)};
        *(uint4*)(Wb + i) = *(const uint4*)hh;
        return;
    }

    const int st = blockIdx.x;          // 64-row s-tile (0..25)
    const int bh = blockIdx.y;
    const int b = bh / NHEAD, h = bh % NHEAD;

    if (z == 1) {                       // V pack (no transpose), 26 tiles
        const float* g = vg + ((size_t)b * CDIM + h * 64) * NSP;
        const float* c = cv + b * CDIM + h * 64;
        const int sl = t & 63, s = st * 64 + sl;
        for (int i = 0; i < 16; ++i) {
            const int d = (t >> 6) * 16 + i;
            float v = 0.f;
            if (s == 0)       v = c[d];
            else if (s < SEQ) v = g[(size_t)d * NSP + s - 1];
            Vb[((size_t)bh * 64 + d) * SPADK + s] = __float2bfloat16(v);
        }
        return;
    }

    // z = 0: K transpose-pack (26 tiles; pads are zeros)
    __shared__ float tile[64 * 65];
    const float* g = kg + ((size_t)b * CDIM + h * 64) * NSP;
    const float* c = ck + b * CDIM + h * 64;

    const int sl = t & 63, s = st * 64 + sl;
    for (int i = 0; i < 16; ++i) {
        const int d = (t >> 6) * 16 + i;
        float v = 0.f;
        if (s == 0)       v = c[d];
        else if (s < SEQ) v = g[(size_t)d * NSP + s - 1];
        tile[d * 65 + sl] = v;
    }
    __syncthreads();
    const size_t rowbase = (size_t)bh * SPADK + st * 64;
    const int d = t & 63;
    for (int i = 0; i < 16; ++i) {
        const int r = i * 4 + (t >> 6);
        Kb[(rowbase + r) * 64 + d] = __float2bfloat16(tile[d * 65 + r]);
    }
}

// ---------------------------------------------------------------------------
// MFMA flash attention — r14 VERBATIM except Q is read fp32 directly from
// the input (+cls) in the prologue (scale 0.125*log2e, cvt bf16 — identical
// numerics to the old qk_pack path), eliminating the Q-pack prepass and Qb.
// 32 strided dword loads/thread, once, hidden under first K staging.
//  (1) XCD-aware bh-grouped 1D grid: 624 = 8 XCD x (6 bh x 13 qt) — K/V
//      L2-local per XCD (FETCH 85.6 -> 15 MB measured in r14).
//  (2) s_setprio(1) around QK and PV MFMA clusters.
// Schedule: 13 chunk-barriers, K dbuf 2x16KB, 4 waves x 32 q, V direct,
// wave-private P, swapped-QK^T, no-rescale exp2 softmax, ones-column sums.
// ---------------------------------------------------------------------------
__global__ __launch_bounds__(256, 3) void attn_mfma(
    const float* __restrict__ qg, const float* __restrict__ cq,
    const __hip_bfloat16* __restrict__ Kbp, const __hip_bfloat16* __restrict__ Vbp,
    __hip_bfloat16* __restrict__ xb)
{
    __shared__ char smem[49152];
    char* const Ksb0 = smem;            // [128 k][64 d] bf16 swizzled, chunk buf 0
    char* const Ksb1 = smem + 16384;    // chunk buf 1

    const int t    = threadIdx.x;
    const int lane = t & 63;
    const int w    = t >> 6;
    const int lo   = lane & 15, hi = lane >> 4;

    // ---- XCD-grouped decode: gid&7 = XCD (round-robin dispatch), each XCD
    //      owns 6 whole bh (slot/13) x 13 q-tiles (slot%13). Bijective: 624=8*78.
    const int gid  = blockIdx.x;
    const int slot = gid >> 3;
    const int bh   = (gid & 7) + 8 * (slot / 13);
    const int qb   = (slot % 13) * 128;
    const int b    = bh / NHEAD, h = bh % NHEAD;

    const unsigned short* Kg = (const unsigned short*)Kbp + (size_t)bh * SPADK * 64;
    const unsigned short* Vg = (const unsigned short*)Vbp + (size_t)bh * 64 * SPADK;

    char* const Pw = smem + 32768 + w * 4096;   // per-wave [32 q][64 k] bf16 swz

    // ---- K staging indices: 128 rows x 64 cols = 1024 x 16B chunks,
    //      256 threads x 4 chunks (rows sr + 32p, col sc)
    const int sr = t >> 3, sc = t & 7;   // sr in [0,32)

    // ---- prologue: chunk 0 -> Ksb0 (issued first: first-barrier critical path)
    uint4 kreg[4];
    #pragma unroll
    for (int p = 0; p < 4; ++p)
        kreg[p] = *(const uint4*)(Kg + (size_t)(sr + 32 * p) * 64 + sc * 8);
    #pragma unroll
    for (int p = 0; p < 4; ++p) {
        const int r = sr + 32 * p;
        *(uint4*)(Ksb0 + r * 128 + ((sc ^ (r & 7)) * 16)) = kreg[p];
    }

    // ---- Q fragments: fp32 direct (+cls), scale, cvt bf16 — once.
    //      Same numerics as the old qk_pack path.
    const float* qc = qg + ((size_t)b * CDIM + h * 64) * NSP;
    const float* cc = cq + b * CDIM + h * 64;
    const float qscale = 0.125f * 1.44269504f;
    bf16x8 qf[2][2];
    #pragma unroll
    for (int qn = 0; qn < 2; ++qn) {
        const int qglob = qb + w * 32 + qn * 16 + lo;
        #pragma unroll
        for (int ks = 0; ks < 2; ++ks)
            #pragma unroll
            for (int i = 0; i < 8; ++i) {
                const int d = (ks * 4 + hi) * 8 + i;
                float v = 0.f;
                if (qglob == 0)       v = cc[d];
                else if (qglob < SEQ) v = qc[(size_t)d * NSP + qglob - 1];
                __hip_bfloat16 hv = __float2bfloat16(v * qscale);
                qf[qn][ks][i] = *(__bf16*)&hv;
            }
    }

    f32x4 o[2][4];          // O accumulators: row q=hi*4+r, col d=dn*16+lo
    f32x4 l5[2];            // row-sum accumulators
    #pragma unroll
    for (int m = 0; m < 2; ++m) {
        l5[m] = (f32x4){0.f, 0.f, 0.f, 0.f};
        #pragma unroll
        for (int n = 0; n < 4; ++n) o[m][n] = (f32x4){0.f, 0.f, 0.f, 0.f};
    }

    bf16x8 ones;
    #pragma unroll
    for (int i = 0; i < 8; ++i) ones[i] = (__bf16)1.0f;

    int cur = 0;

    for (int it = 0; it < 13; ++it) {
        __syncthreads();                        // chunk[cur] staged for all waves
        char* const Kcur = cur ? Ksb1 : Ksb0;
        char* const Knxt = cur ? Ksb0 : Ksb1;

        // prefetch next 128-key chunk into regs (clamped; last iter redundant)
        const int itn = (it + 1 < 13) ? it + 1 : it;
        #pragma unroll
        for (int p = 0; p < 4; ++p)
            kreg[p] = *(const uint4*)(Kg + (size_t)(itn * 128 + sr + 32 * p) * 64 + sc * 8);

        // ---- two 64-key subtiles from the staged chunk
        #pragma unroll
        for (int sub = 0; sub < 2; ++sub) {
            const int kb = it * 128 + sub * 64;
            char* const Ksub = Kcur + sub * 8192;

            // V fragments ks=0 (direct global, B-frag)
            uint4 vf0[4];
            #pragma unroll
            for (int dn = 0; dn < 4; ++dn)
                vf0[dn] = *(const uint4*)(Vg + (size_t)(dn * 16 + lo) * SPADK + kb + hi * 8);

            // ---- S^T = K Q^T  (prio-boosted MFMA cluster)
            f32x4 s[4][2];
            #pragma unroll
            for (int km = 0; km < 4; ++km)
                #pragma unroll
                for (int qn = 0; qn < 2; ++qn) s[km][qn] = (f32x4){0.f, 0.f, 0.f, 0.f};
            __builtin_amdgcn_s_setprio(1);
            #pragma unroll
            for (int ks = 0; ks < 2; ++ks) {
                bf16x8 ak[4];
                #pragma unroll
                for (int km = 0; km < 4; ++km)
                    ak[km] = *(const bf16x8*)(Ksub + (km * 16 + lo) * 128 + (((ks * 4 + hi) ^ (lo & 7)) * 16));
                #pragma unroll
                for (int km = 0; km < 4; ++km)
                    #pragma unroll
                    for (int qn = 0; qn < 2; ++qn)
                        s[km][qn] = __builtin_amdgcn_mfma_f32_16x16x32_bf16(ak[km], qf[qn][ks], s[km][qn], 0, 0, 0);
            }
            __builtin_amdgcn_s_setprio(0);

            if (it == 12) {                     // chunk 12: keys 1536..1663, mask k >= SEQ
                #pragma unroll
                for (int km = 0; km < 4; ++km)
                    #pragma unroll
                    for (int r = 0; r < 4; ++r)
                        if (kb + km * 16 + hi * 4 + r >= SEQ) {
                            s[km][0][r] = -1e30f;
                            s[km][1][r] = -1e30f;
                        }
            }

            // ---- P = exp2(S); packed b64 writes into Pw[q][k] (swizzled)
            #pragma unroll
            for (int qn = 0; qn < 2; ++qn)
                #pragma unroll
                for (int km = 0; km < 4; ++km) {
                    const float p0 = exp2f(s[km][qn][0]);
                    const float p1 = exp2f(s[km][qn][1]);
                    const float p2 = exp2f(s[km][qn][2]);
                    const float p3 = exp2f(s[km][qn][3]);
                    uint2 pk;
                    pk.x = pkbf(p0, p1);
                    pk.y = pkbf(p2, p3);
                    const int row = qn * 16 + lo;
                    *(uint2*)(Pw + row * 128 + (((km * 2 + (hi >> 1)) ^ (lo & 7)) * 16) + (hi & 1) * 8) = pk;
                }

            // V fragments ks=1
            uint4 vf1[4];
            #pragma unroll
            for (int dn = 0; dn < 4; ++dn)
                vf1[dn] = *(const uint4*)(Vg + (size_t)(dn * 16 + lo) * SPADK + kb + 32 + hi * 8);

            // ---- O += P V ; l += P * ones  (prio-boosted MFMA cluster)
            __builtin_amdgcn_s_setprio(1);
            #pragma unroll
            for (int ks = 0; ks < 2; ++ks) {
                bf16x8 ap[2];
                #pragma unroll
                for (int m = 0; m < 2; ++m)
                    ap[m] = *(const bf16x8*)(Pw + (m * 16 + lo) * 128 + (((ks * 4 + hi) ^ (lo & 7)) * 16));
                #pragma unroll
                for (int m = 0; m < 2; ++m) {
                    #pragma unroll
                    for (int dn = 0; dn < 4; ++dn) {
                        const bf16x8 bv = *(const bf16x8*)(ks ? &vf1[dn] : &vf0[dn]);
                        o[m][dn] = __builtin_amdgcn_mfma_f32_16x16x32_bf16(ap[m], bv, o[m][dn], 0, 0, 0);
                    }
                    l5[m] = __builtin_amdgcn_mfma_f32_16x16x32_bf16(ap[m], ones, l5[m], 0, 0, 0);
                }
            }
            __builtin_amdgcn_s_setprio(0);
        }

        // stage next chunk into the other buffer (visible after next barrier)
        #pragma unroll
        for (int p = 0; p < 4; ++p) {
            const int r = sr + 32 * p;
            *(uint4*)(Knxt + r * 128 + ((sc ^ (r & 7)) * 16)) = kreg[p];
        }
        cur ^= 1;
    }

    // ---- epilogue: normalize by row sum, direct bf16 stores to xb[n][ci]
    #pragma unroll
    for (int m = 0; m < 2; ++m)
        #pragma unroll
        for (int r = 0; r < 4; ++r) {
            const float inv = 1.f / l5[m][r];
            const int q = qb + w * 32 + m * 16 + hi * 4 + r;
            if (q < SEQ) {
                __hip_bfloat16* dst = xb + ((size_t)b * SEQ + q) * CDIM + h * 64 + lo;
                #pragma unroll
                for (int dn = 0; dn < 4; ++dn)
                    dst[dn * 16] = __float2bfloat16(o[m][dn][r] * inv);
            }
        }
}

// ---------------------------------------------------------------------------
// MFMA projection, 128co x 64n tiles, XCD-GROUPED 1D GRID: 600 slots
// (8 XCD x 75), id = (gid&7)*75 + (gid>>3), guard id>=594. Consecutive
// slots on one XCD share the same 196KB W panel and stream contiguous x
// tiles -> W/x re-reads become local-L2 hits (same T1 mechanism that cut
// attn FETCH 5.7x in r14). Body unchanged from r12.
// ---------------------------------------------------------------------------
__global__ __launch_bounds__(256) void proj_mfma(
    const __hip_bfloat16* __restrict__ Wb, const __hip_bfloat16* __restrict__ xbp,
    const float* __restrict__ bias, float* __restrict__ xout,
    float* __restrict__ clsout)
{
    __shared__ char smem[24576];
    char* Ws = smem;            // [128 co][64 k] bf16, swizzled
    char* Xs = smem + 16384;    // [ 64 n][64 k] bf16, swizzled

    const int id = ((int)blockIdx.x & 7) * 75 + ((int)blockIdx.x >> 3);
    if (id >= 594) return;
    const int mb = (id / 99) * 128;
    const int nb = (id % 99) * 64;

    const int t    = threadIdx.x;
    const int lane = t & 63;
    const int w    = t >> 6;
    const int lo   = lane & 15, hi = lane >> 4;

    const unsigned short* Wg = (const unsigned short*)Wb  + (size_t)mb * CDIM;
    const unsigned short* Xg = (const unsigned short*)xbp + (size_t)nb * CDIM;

    f32x4 acc[4][2];
    #pragma unroll
    for (int m = 0; m < 4; ++m)
        #pragma unroll
        for (int n = 0; n < 2; ++n) acc[m][n] = (f32x4){0.f, 0.f, 0.f, 0.f};

    const bool xok[2] = { nb + ((t)       >> 3) < NTOT,
                          nb + ((t + 256) >> 3) < NTOT };
    uint4 wreg[4], xreg[2];
    #pragma unroll
    for (int p = 0; p < 4; ++p) {
        const int ch = t + 256 * p;
        wreg[p] = *(const uint4*)(Wg + (ch >> 3) * CDIM + (ch & 7) * 8);
    }
    #pragma unroll
    for (int p = 0; p < 2; ++p) {
        const int ch = t + 256 * p;
        xreg[p] = xok[p] ? *(const uint4*)(Xg + (ch >> 3) * CDIM + (ch & 7) * 8)
                         : (uint4){0u, 0u, 0u, 0u};
    }

    for (int kt = 0; kt < 12; ++kt) {
        __syncthreads();
        #pragma unroll
        for (int p = 0; p < 4; ++p) {
            const int ch = t + 256 * p;
            const int r = ch >> 3, c = ch & 7;
            *(uint4*)(Ws + r * 128 + ((c ^ (r & 7)) * 16)) = wreg[p];
        }
        #pragma unroll
        for (int p = 0; p < 2; ++p) {
            const int ch = t + 256 * p;
            const int r = ch >> 3, c = ch & 7;
            *(uint4*)(Xs + r * 128 + ((c ^ (r & 7)) * 16)) = xreg[p];
        }
        __syncthreads();
        if (kt + 1 < 12) {
            const int kb = (kt + 1) * 64;
            #pragma unroll
            for (int p = 0; p < 4; ++p) {
                const int ch = t + 256 * p;
                wreg[p] = *(const uint4*)(Wg + (ch >> 3) * CDIM + kb + (ch & 7) * 8);
            }
            #pragma unroll
            for (int p = 0; p < 2; ++p) {
                const int ch = t + 256 * p;
                xreg[p] = xok[p] ? *(const uint4*)(Xg + (ch >> 3) * CDIM + kb + (ch & 7) * 8)
                                 : (uint4){0u, 0u, 0u, 0u};
            }
        }
        #pragma unroll
        for (int ks = 0; ks < 2; ++ks) {
            bf16x8 aw[4], bx[2];
            #pragma unroll
            for (int m = 0; m < 4; ++m) {
                const int row = (w >> 1) * 64 + m * 16 + lo;
                aw[m] = *(const bf16x8*)(Ws + row * 128 + (((ks * 4 + hi) ^ (lo & 7)) * 16));
            }
            #pragma unroll
            for (int n = 0; n < 2; ++n) {
                const int row = (w & 1) * 32 + n * 16 + lo;
                bx[n] = *(const bf16x8*)(Xs + row * 128 + (((ks * 4 + hi) ^ (lo & 7)) * 16));
            }
            #pragma unroll
            for (int m = 0; m < 4; ++m)
                #pragma unroll
                for (int n = 0; n < 2; ++n)
                    acc[m][n] = __builtin_amdgcn_mfma_f32_16x16x32_bf16(aw[m], bx[n], acc[m][n], 0, 0, 0);
        }
    }

    // ---- epilogue: bias, scatter (s==0 -> cls, else spatial, co-major)
    const int cob = mb + (w >> 1) * 64;
    const int nbb = nb + (w & 1) * 32;
    #pragma unroll
    for (int m = 0; m < 4; ++m)
        #pragma unroll
        for (int r = 0; r < 4; ++r) {
            const int co = cob + m * 16 + hi * 4 + r;
            const float bv = bias[co];
            #pragma unroll
            for (int n4 = 0; n4 < 2; ++n4) {
                const int n = nbb + n4 * 16 + lo;
                if (n >= NTOT) continue;
                const int bq = n / SEQ;
                const int s  = n - bq * SEQ;
                const float val = acc[m][n4][r] + bv;
                if (s == 0) clsout[bq * CDIM + co] = val;
                else        xout[((size_t)bq * CDIM + co) * NSP + (s - 1)] = val;
            }
        }
}

extern "C" void kernel_launch(void* const* d_in, const int* in_sizes, int n_in,
                              void* d_out, int out_size, void* d_ws, size_t ws_size,
                              hipStream_t stream)
{
    const float* q  = (const float*)d_in[0];
    const float* k  = (const float*)d_in[1];
    const float* v  = (const float*)d_in[2];
    const float* cq = (const float*)d_in[3];
    const float* ck = (const float*)d_in[4];
    const float* cv = (const float*)d_in[5];
    const float* W  = (const float*)d_in[6];
    const float* bi = (const float*)d_in[7];

    float* out    = (float*)d_out;
    float* xout   = out;
    float* clsout = out + (size_t)BATCH * CDIM * NSP;

    __hip_bfloat16* Kb = (__hip_bfloat16*)d_ws;                 // 10.2 MB
    __hip_bfloat16* Vb = Kb + (size_t)NBH * SPADK * 64;         // 10.2 MB
    __hip_bfloat16* Wb = Vb + (size_t)NBH * 64 * SPADK;         //  1.2 MB
    __hip_bfloat16* xb = Wb + (size_t)CDIM * CDIM;              //  9.6 MB

    pack_all <<<dim3(26, NBH, 3), 256, 0, stream>>>(k, v, ck, cv, W, Kb, Vb, Wb);
    attn_mfma<<<dim3(624),        256, 0, stream>>>(q, cq, Kb, Vb, xb);
    proj_mfma<<<dim3(600),        256, 0, stream>>>(Wb, xb, bi, xout, clsout);
}